// Round 1
// baseline (16140.398 us; speedup 1.0000x reference)
//
#include <hip/hip_runtime.h>

// BiLSTM tagger, MI355X. Round 0: correctness-first, all fp32.
//
// Pipeline (all on `stream`):
//   k_prep      : preC[cv][512] = char_Wih @ char_emb[cv] + char_b ; whhTc = char_Whh^T
//   k_char_lstm : batched 16-step char LSTM (16 words/block), emits embeds[:,0:128]
//   k_gather    : embeds[:,128:384] = word_emb[sentence]
//   k_pregate   : pregates[dir][t][1024] = embeds[t] @ Wih_dir^T + b_dir   (hoisted x-part)
//   k_recurrent : 16 WGs (8 fw + 8 bw). Whh slice in VGPRs; per-step h exchange via
//                 tagged u64 agent-scope atomics (tag = step+1, poison-safe equality check,
//                 parity double buffer; max producer/consumer skew = 1 step).
//   k_output    : logits + log_softmax
//
// Workspace (d_ws) needs ~92.5 MB:
//   [0)          preC      256 KB
//   [262144)     whhTc     256 KB
//   [524288)     embeds    12 MB   [8192][384]
//   [13107200)   pregates  64 MB   [2][8192][1024]
//   [80216064)   hout      16 MB   [8192][512]  ([hf|hb])
//   [96993280)   hbuf      8 KB    [2][2][256] u64 tagged h

#define S_LEN 8192
#define LC    16
#define DW    256
#define DC    64
#define HC    128
#define H2    256
#define NG    1024   // 4*H2
#define NTAG  64
#define CV    128

__device__ __forceinline__ float sigmoidf_(float x){ return 1.0f/(1.0f + expf(-x)); }

// ---------------------------------------------------------------- k_prep
__global__ __launch_bounds__(512) void k_prep(
    const float* __restrict__ char_emb, const float* __restrict__ char_Wih,
    const float* __restrict__ char_Whh, const float* __restrict__ char_b,
    float* __restrict__ preC, float* __restrict__ whhTc)
{
  int blk = blockIdx.x, tid = threadIdx.x;
  __shared__ float esh[DC];
  if (blk < CV){
    if (tid < DC) esh[tid] = char_emb[blk*DC + tid];
    __syncthreads();
    const float* wr = char_Wih + (size_t)tid*DC;
    float acc = char_b[tid];
#pragma unroll
    for (int d=0; d<DC; d+=4){
      float4 wv = *(const float4*)&wr[d];
      acc += wv.x*esh[d] + wv.y*esh[d+1] + wv.z*esh[d+2] + wv.w*esh[d+3];
    }
    preC[(size_t)blk*512 + tid] = acc;
  } else {
    int k = blk - CV;                       // 0..127
    whhTc[(size_t)k*512 + tid] = char_Whh[(size_t)tid*HC + k];
  }
}

// ---------------------------------------------------------------- k_char_lstm
// 16 words/block, 512 blocks. Thread owns 2 gate rows (g, g+256) for all 16 words.
__global__ __launch_bounds__(256) void k_char_lstm(
    const int* __restrict__ charsets, const int* __restrict__ lengths,
    const float* __restrict__ preC, const float* __restrict__ whhTc,
    float* __restrict__ embeds)
{
  int blk = blockIdx.x, tid = threadIdx.x;
  int s0 = blk*16;
  __shared__ float h_sh[16][132];           // padded rows, fp32 h
  __shared__ float gsh[512][17];            // gate preacts [gate][word], pad 17 (conflict-free)
  __shared__ int   ch_sh[16];

  for (int i = tid; i < 16*132; i += 256) (&h_sh[0][0])[i] = 0.0f;

  int uw  = tid & 15;                       // update: word
  int ujg = tid >> 4;                       // update: j = ujg*8+u
  float c[8];
#pragma unroll
  for (int u=0; u<8; u++) c[u] = 0.0f;
  int lw = lengths[s0 + uw];

  int g0 = tid, g1 = tid + 256;
  __syncthreads();

  for (int t=0; t<LC; t++){
    if (tid < 16) ch_sh[tid] = charsets[(size_t)(s0+tid)*LC + t];
    __syncthreads();                                        // (A)

    float acc0[16], acc1[16];
#pragma unroll
    for (int w=0; w<16; w++){
      int ch = ch_sh[w];
      acc0[w] = preC[(size_t)ch*512 + g0];
      acc1[w] = preC[(size_t)ch*512 + g1];
    }
    for (int k4=0; k4<HC; k4+=4){
      float w00 = whhTc[(size_t)(k4+0)*512 + g0];
      float w01 = whhTc[(size_t)(k4+1)*512 + g0];
      float w02 = whhTc[(size_t)(k4+2)*512 + g0];
      float w03 = whhTc[(size_t)(k4+3)*512 + g0];
      float w10 = whhTc[(size_t)(k4+0)*512 + g1];
      float w11 = whhTc[(size_t)(k4+1)*512 + g1];
      float w12 = whhTc[(size_t)(k4+2)*512 + g1];
      float w13 = whhTc[(size_t)(k4+3)*512 + g1];
#pragma unroll
      for (int w=0; w<16; w++){
        float4 h4 = *(const float4*)&h_sh[w][k4];
        acc0[w] += w00*h4.x + w01*h4.y + w02*h4.z + w03*h4.w;
        acc1[w] += w10*h4.x + w11*h4.y + w12*h4.z + w13*h4.w;
      }
    }
#pragma unroll
    for (int w=0; w<16; w++){ gsh[g0][w] = acc0[w]; gsh[g1][w] = acc1[w]; }
    __syncthreads();                                        // (G)

    float hnew[8];
#pragma unroll
    for (int u=0; u<8; u++){
      int j = ujg*8 + u;
      float gi = sigmoidf_(gsh[j][uw]);
      float gf = sigmoidf_(gsh[HC + j][uw]);
      float gg = tanhf   (gsh[2*HC + j][uw]);
      float go = sigmoidf_(gsh[3*HC + j][uw]);
      c[u] = gf*c[u] + gi*gg;
      hnew[u] = go * tanhf(c[u]);
    }
    // h_sh writes are safe: all compute-phase h_sh reads finished before (G);
    // gsh reads here are protected from next step's writes by next iter's (A).
#pragma unroll
    for (int u=0; u<8; u+=4)
      *(float4*)&h_sh[uw][ujg*8 + u] = make_float4(hnew[u],hnew[u+1],hnew[u+2],hnew[u+3]);
    if (t == lw-1){
#pragma unroll
      for (int u=0; u<8; u+=4)
        *(float4*)&embeds[(size_t)(s0+uw)*384 + ujg*8 + u]
            = make_float4(hnew[u],hnew[u+1],hnew[u+2],hnew[u+3]);
    }
  }
}

// ---------------------------------------------------------------- k_gather
__global__ __launch_bounds__(256) void k_gather(
    const int* __restrict__ sentence, const float* __restrict__ word_emb,
    float* __restrict__ embeds)
{
  int blk = blockIdx.x, tid = threadIdx.x;
  int s = blk*8 + (tid >> 5);
  int lane = tid & 31;
  int idx = sentence[s];
  const float4* src = (const float4*)(word_emb + (size_t)idx*DW);
  float4* dst = (float4*)(embeds + (size_t)s*384 + 128);
  dst[lane]      = src[lane];
  dst[lane + 32] = src[lane + 32];
}

// ---------------------------------------------------------------- k_pregate
// pregates[dir][t][n] = sum_k embeds[t][k]*Wih_dir[n][k] + b_dir[n]
__global__ __launch_bounds__(256) void k_pregate(
    const float* __restrict__ embeds,
    const float* __restrict__ Wih_fw, const float* __restrict__ b_fw,
    const float* __restrict__ Wih_bw, const float* __restrict__ b_bw,
    float* __restrict__ pregates)
{
  int dir = blockIdx.z;
  const float* W    = dir ? Wih_bw : Wih_fw;
  const float* bias = dir ? b_bw   : b_fw;
  int t0 = blockIdx.x*64, n0 = blockIdx.y*64;
  __shared__ float a_sh[16][68];
  __shared__ float b_sh[16][68];
  int tid = threadIdx.x;
  int li = tid & 63, kq = tid >> 6;
  int ti = tid >> 4, tj = tid & 15;
  float acc[4][4];
#pragma unroll
  for (int ii=0; ii<4; ii++)
#pragma unroll
    for (int jj=0; jj<4; jj++) acc[ii][jj] = 0.0f;

  for (int k0=0; k0<384; k0+=16){
    float4 av = *(const float4*)&embeds[(size_t)(t0+li)*384 + k0 + kq*4];
    float4 bv = *(const float4*)&W     [(size_t)(n0+li)*384 + k0 + kq*4];
    __syncthreads();
    a_sh[kq*4+0][li]=av.x; a_sh[kq*4+1][li]=av.y; a_sh[kq*4+2][li]=av.z; a_sh[kq*4+3][li]=av.w;
    b_sh[kq*4+0][li]=bv.x; b_sh[kq*4+1][li]=bv.y; b_sh[kq*4+2][li]=bv.z; b_sh[kq*4+3][li]=bv.w;
    __syncthreads();
#pragma unroll
    for (int kk=0; kk<16; kk++){
      float4 a4 = *(const float4*)&a_sh[kk][ti*4];
      float4 b4 = *(const float4*)&b_sh[kk][tj*4];
      float aa[4] = {a4.x,a4.y,a4.z,a4.w};
      float bb[4] = {b4.x,b4.y,b4.z,b4.w};
#pragma unroll
      for (int ii=0; ii<4; ii++)
#pragma unroll
        for (int jj=0; jj<4; jj++) acc[ii][jj] += aa[ii]*bb[jj];
    }
  }
  float4 bias4 = *(const float4*)&bias[n0 + tj*4];
  float bb2[4] = {bias4.x,bias4.y,bias4.z,bias4.w};
#pragma unroll
  for (int ii=0; ii<4; ii++){
    float4 o = make_float4(acc[ii][0]+bb2[0], acc[ii][1]+bb2[1],
                           acc[ii][2]+bb2[2], acc[ii][3]+bb2[3]);
    *(float4*)&pregates[((size_t)dir*S_LEN + (t0+ti*4+ii))*NG + n0 + tj*4] = o;
  }
}

// ---------------------------------------------------------------- k_recurrent
// grid = 16: WG(wg): dir = wg>>3, slice g = wg&7 owns h-units j in [32g,32g+32).
// Thread (r4 = tid>>3, ke = tid&7): rows 4*r4..4*r4+3 of the 128-row slice,
// k in [32*ke, 32*ke+32). Whh slice lives in w[4][32] registers.
__global__ __launch_bounds__(256) void k_recurrent(
    const float* __restrict__ Whh_fw, const float* __restrict__ Whh_bw,
    const float* __restrict__ pregates,
    unsigned long long* hbuf,
    float* __restrict__ hout)
{
  int wg = blockIdx.x; int dir = wg >> 3; int g = wg & 7;
  int tid = threadIdx.x;
  const float* Whh = dir ? Whh_bw : Whh_fw;
  const float* pgb = pregates + (size_t)dir * S_LEN * NG;
  unsigned long long* hb = hbuf + (size_t)dir * 2 * H2;

  __shared__ float h_sh[H2];
  __shared__ float gacc[128];

  int r4 = tid >> 3, ke = tid & 7;
  int q   = r4 >> 3;                 // gate block 0..3 (i,f,g,o)
  int jj4 = (4*r4) & 31;
  int row0 = q*H2 + g*32 + jj4;      // global gate row of rr=0

  float w[4][32];
#pragma unroll
  for (int rr=0; rr<4; rr++){
    const float* wr = Whh + (size_t)(row0+rr)*H2 + ke*32;
#pragma unroll
    for (int kq=0; kq<8; kq++){
      float4 v = *(const float4*)&wr[kq*4];
      w[rr][kq*4+0]=v.x; w[rr][kq*4+1]=v.y; w[rr][kq*4+2]=v.z; w[rr][kq*4+3]=v.w;
    }
  }
  float c = 0.0f;
  h_sh[tid] = 0.0f;                  // h_{-1} = 0 (tid < 256 == H2)
  __syncthreads();

  for (int sstep=0; sstep<S_LEN; sstep++){
    int t = dir ? (S_LEN-1-sstep) : sstep;
    float4 pg = make_float4(0.f,0.f,0.f,0.f);
    if (ke == 0) pg = *(const float4*)&pgb[(size_t)t*NG + row0];

    float a0=0.f, a1=0.f, a2=0.f, a3=0.f;
    const float* hk = &h_sh[ke*32];
#pragma unroll
    for (int kq=0; kq<8; kq++){
      float4 h4 = *(const float4*)&hk[kq*4];
      a0 += w[0][kq*4+0]*h4.x + w[0][kq*4+1]*h4.y + w[0][kq*4+2]*h4.z + w[0][kq*4+3]*h4.w;
      a1 += w[1][kq*4+0]*h4.x + w[1][kq*4+1]*h4.y + w[1][kq*4+2]*h4.z + w[1][kq*4+3]*h4.w;
      a2 += w[2][kq*4+0]*h4.x + w[2][kq*4+1]*h4.y + w[2][kq*4+2]*h4.z + w[2][kq*4+3]*h4.w;
      a3 += w[3][kq*4+0]*h4.x + w[3][kq*4+1]*h4.y + w[3][kq*4+2]*h4.z + w[3][kq*4+3]*h4.w;
    }
    // reduce over ke (8 lanes, low bits of lane id)
    a0 += __shfl_xor(a0,1); a1 += __shfl_xor(a1,1); a2 += __shfl_xor(a2,1); a3 += __shfl_xor(a3,1);
    a0 += __shfl_xor(a0,2); a1 += __shfl_xor(a1,2); a2 += __shfl_xor(a2,2); a3 += __shfl_xor(a3,2);
    a0 += __shfl_xor(a0,4); a1 += __shfl_xor(a1,4); a2 += __shfl_xor(a2,4); a3 += __shfl_xor(a3,4);
    if (ke == 0)
      *(float4*)&gacc[r4*4] = make_float4(a0+pg.x, a1+pg.y, a2+pg.z, a3+pg.w);
    __syncthreads();

    if (tid < 32){
      float gi = sigmoidf_(gacc[tid]);
      float gf = sigmoidf_(gacc[32+tid]);
      float gg = tanhf   (gacc[64+tid]);
      float go = sigmoidf_(gacc[96+tid]);
      c = gf*c + gi*gg;
      float hn = go * tanhf(c);
      unsigned long long pack =
          ((unsigned long long)__float_as_uint(hn) << 32) | (unsigned long long)(unsigned)(sstep+1);
      __hip_atomic_store(&hb[(sstep&1)*H2 + g*32 + tid], pack,
                         __ATOMIC_RELAXED, __HIP_MEMORY_SCOPE_AGENT);
      hout[(size_t)t*512 + dir*H2 + g*32 + tid] = hn;
    }
    // poll own word of the full h vector (self-validating tag)
    {
      unsigned tag = (unsigned)(sstep+1);
      unsigned long long* slot = &hb[(sstep&1)*H2 + tid];
      unsigned long long vv;
      do {
        vv = __hip_atomic_load(slot, __ATOMIC_RELAXED, __HIP_MEMORY_SCOPE_AGENT);
      } while ((unsigned)vv != tag);
      h_sh[tid] = __uint_as_float((unsigned)(vv >> 32));
    }
    __syncthreads();
  }
}

// ---------------------------------------------------------------- k_output
__global__ __launch_bounds__(256) void k_output(
    const float* __restrict__ hout, const float* __restrict__ outW,
    const float* __restrict__ outb, float* __restrict__ out)
{
  __shared__ float wT[128][66];
  __shared__ float hsh[32][132];
  __shared__ float lsh[32][66];
  __shared__ float msh[32][2];
  int t0 = blockIdx.x*32, tid = threadIdx.x;
  int n  = tid & 63, tg = tid >> 6;
  int sl = tid >> 3, kg = tid & 7;
  int wn = tid & 63, wk = tid >> 6;
  float acc[8];
#pragma unroll
  for (int u=0; u<8; u++) acc[u] = 0.0f;

  for (int kc=0; kc<4; kc++){
    int k0 = kc*128;
    float4 wreg[8];
#pragma unroll
    for (int e=0; e<8; e++) wreg[e] = *(const float4*)&outW[(size_t)wn*512 + k0 + wk*32 + e*4];
    float4 hreg[4];
#pragma unroll
    for (int e=0; e<4; e++) hreg[e] = *(const float4*)&hout[(size_t)(t0+sl)*512 + k0 + kg*16 + e*4];
    __syncthreads();
#pragma unroll
    for (int e=0; e<8; e++){
      int kk = wk*32 + e*4;
      wT[kk+0][wn]=wreg[e].x; wT[kk+1][wn]=wreg[e].y; wT[kk+2][wn]=wreg[e].z; wT[kk+3][wn]=wreg[e].w;
    }
#pragma unroll
    for (int e=0; e<4; e++) *(float4*)&hsh[sl][kg*16 + e*4] = hreg[e];
    __syncthreads();
#pragma unroll
    for (int kk4=0; kk4<128; kk4+=4){
      float w0 = wT[kk4+0][n], w1 = wT[kk4+1][n], w2 = wT[kk4+2][n], w3 = wT[kk4+3][n];
#pragma unroll
      for (int u=0; u<8; u++){
        float4 h4 = *(const float4*)&hsh[tg*8+u][kk4];
        acc[u] += w0*h4.x + w1*h4.y + w2*h4.z + w3*h4.w;
      }
    }
  }
  float bn = outb[n];
#pragma unroll
  for (int u=0; u<8; u++) lsh[tg*8+u][n] = acc[u] + bn;
  __syncthreads();
  if (tid < 32){
    float M = -3.4e38f;
    for (int j=0; j<NTAG; j++) M = fmaxf(M, lsh[tid][j]);
    float ssum = 0.0f;
    for (int j=0; j<NTAG; j++) ssum += expf(lsh[tid][j] - M);
    msh[tid][0] = M; msh[tid][1] = logf(ssum);
  }
  __syncthreads();
#pragma unroll
  for (int u=0; u<8; u++){
    int tt = tg*8+u;
    out[(size_t)(t0+tt)*NTAG + n] = lsh[tt][n] - msh[tt][0] - msh[tt][1];
  }
}

// ---------------------------------------------------------------- launch
extern "C" void kernel_launch(void* const* d_in, const int* in_sizes, int n_in,
                              void* d_out, int out_size, void* d_ws, size_t ws_size,
                              hipStream_t stream)
{
  (void)in_sizes; (void)n_in; (void)out_size; (void)ws_size;
  const int*   sentence = (const int*)d_in[0];
  const int*   charsets = (const int*)d_in[1];
  const int*   char_len = (const int*)d_in[2];
  const float* word_emb = (const float*)d_in[3];
  const float* char_emb = (const float*)d_in[4];
  const float* char_Wih = (const float*)d_in[5];
  const float* char_Whh = (const float*)d_in[6];
  const float* char_b   = (const float*)d_in[7];
  const float* fw_Wih   = (const float*)d_in[8];
  const float* fw_Whh   = (const float*)d_in[9];
  const float* fw_b     = (const float*)d_in[10];
  const float* bw_Wih   = (const float*)d_in[11];
  const float* bw_Whh   = (const float*)d_in[12];
  const float* bw_b     = (const float*)d_in[13];
  const float* out_W    = (const float*)d_in[14];
  const float* out_b    = (const float*)d_in[15];
  float* out = (float*)d_out;

  char* ws = (char*)d_ws;
  float* preC     = (float*)(ws);
  float* whhTc    = (float*)(ws + 262144);
  float* embeds   = (float*)(ws + 524288);
  float* pregates = (float*)(ws + 13107200);
  float* houtb    = (float*)(ws + 80216064);
  unsigned long long* hbuf = (unsigned long long*)(ws + 96993280);

  k_prep     <<<256,  512, 0, stream>>>(char_emb, char_Wih, char_Whh, char_b, preC, whhTc);
  k_char_lstm<<<512,  256, 0, stream>>>(charsets, char_len, preC, whhTc, embeds);
  k_gather   <<<1024, 256, 0, stream>>>(sentence, word_emb, embeds);
  k_pregate  <<<dim3(128,16,2), 256, 0, stream>>>(embeds, fw_Wih, fw_b, bw_Wih, bw_b, pregates);
  k_recurrent<<<16,   256, 0, stream>>>(fw_Whh, bw_Whh, pregates, hbuf, houtb);
  k_output   <<<256,  256, 0, stream>>>(houtb, out_W, out_b, out);
}

// Round 2
// 13108.073 us; speedup vs baseline: 1.2313x; 1.2313x over previous
//
#include <hip/hip_runtime.h>

// BiLSTM tagger, MI355X. Round 1: fix k_recurrent (95% of runtime).
//  - __launch_bounds__(256,1): keep 128-float Whh slice resident in VGPRs (was re-streamed from L2)
//  - padded h_sh layout ph(k)=(k>>5)*36+(k&31): conflict-free ds_read_b128 (was 8-way)
//  - single-wave poll of the tagged h exchange (was 256 threads x 16 WGs hammering 2KB)
//  - XCD co-location heuristic: launch 64 blocks, workers are b%8==0 (fw) / b%8==1 (bw)
//    so each direction's 8 WGs land on one XCD under round-robin dispatch
//  - pregate prefetch one step ahead; fast exp-based sigmoid/tanh
//
// Workspace (d_ws) ~92.5 MB:
//   [0)          preC      256 KB
//   [262144)     whhTc     256 KB
//   [524288)     embeds    12 MB   [8192][384]
//   [13107200)   pregates  64 MB   [2][8192][1024]
//   [80216064)   hout      16 MB   [8192][512]  ([hf|hb])
//   [96993280)   hbuf      8 KB    [2][2][256] u64 tagged h (poison-safe: tag equality vs 1..8192)

#define S_LEN 8192
#define LC    16
#define DW    256
#define DC    64
#define HC    128
#define H2    256
#define NG    1024   // 4*H2
#define NTAG  64
#define CV    128

__device__ __forceinline__ float sigmoid_f(float x){
  // 1/(1+e^-x); __expf saturates cleanly: x<<0 -> inf -> 0 ; x>>0 -> 0 -> 1
  return __frcp_rn(1.0f + __expf(-x));
}
__device__ __forceinline__ float tanh_f(float x){
  // tanh(x) = sign(x) * (1 - 2/(e^{2|x|}+1)); e^inf -> inf -> 1, no NaN
  float a = fabsf(x);
  float t = 1.0f - 2.0f * __frcp_rn(__expf(2.0f*a) + 1.0f);
  return copysignf(t, x);
}
__device__ __forceinline__ float sigmoidf_(float x){ return 1.0f/(1.0f + expf(-x)); }

// ---------------------------------------------------------------- k_prep
__global__ __launch_bounds__(512) void k_prep(
    const float* __restrict__ char_emb, const float* __restrict__ char_Wih,
    const float* __restrict__ char_Whh, const float* __restrict__ char_b,
    float* __restrict__ preC, float* __restrict__ whhTc)
{
  int blk = blockIdx.x, tid = threadIdx.x;
  __shared__ float esh[DC];
  if (blk < CV){
    if (tid < DC) esh[tid] = char_emb[blk*DC + tid];
    __syncthreads();
    const float* wr = char_Wih + (size_t)tid*DC;
    float acc = char_b[tid];
#pragma unroll
    for (int d=0; d<DC; d+=4){
      float4 wv = *(const float4*)&wr[d];
      acc += wv.x*esh[d] + wv.y*esh[d+1] + wv.z*esh[d+2] + wv.w*esh[d+3];
    }
    preC[(size_t)blk*512 + tid] = acc;
  } else {
    int k = blk - CV;                       // 0..127
    whhTc[(size_t)k*512 + tid] = char_Whh[(size_t)tid*HC + k];
  }
}

// ---------------------------------------------------------------- k_char_lstm
__global__ __launch_bounds__(256) void k_char_lstm(
    const int* __restrict__ charsets, const int* __restrict__ lengths,
    const float* __restrict__ preC, const float* __restrict__ whhTc,
    float* __restrict__ embeds)
{
  int blk = blockIdx.x, tid = threadIdx.x;
  int s0 = blk*16;
  __shared__ float h_sh[16][132];
  __shared__ float gsh[512][17];
  __shared__ int   ch_sh[16];

  for (int i = tid; i < 16*132; i += 256) (&h_sh[0][0])[i] = 0.0f;

  int uw  = tid & 15;
  int ujg = tid >> 4;
  float c[8];
#pragma unroll
  for (int u=0; u<8; u++) c[u] = 0.0f;
  int lw = lengths[s0 + uw];

  int g0 = tid, g1 = tid + 256;
  __syncthreads();

  for (int t=0; t<LC; t++){
    if (tid < 16) ch_sh[tid] = charsets[(size_t)(s0+tid)*LC + t];
    __syncthreads();                                        // (A)

    float acc0[16], acc1[16];
#pragma unroll
    for (int w=0; w<16; w++){
      int ch = ch_sh[w];
      acc0[w] = preC[(size_t)ch*512 + g0];
      acc1[w] = preC[(size_t)ch*512 + g1];
    }
    for (int k4=0; k4<HC; k4+=4){
      float w00 = whhTc[(size_t)(k4+0)*512 + g0];
      float w01 = whhTc[(size_t)(k4+1)*512 + g0];
      float w02 = whhTc[(size_t)(k4+2)*512 + g0];
      float w03 = whhTc[(size_t)(k4+3)*512 + g0];
      float w10 = whhTc[(size_t)(k4+0)*512 + g1];
      float w11 = whhTc[(size_t)(k4+1)*512 + g1];
      float w12 = whhTc[(size_t)(k4+2)*512 + g1];
      float w13 = whhTc[(size_t)(k4+3)*512 + g1];
#pragma unroll
      for (int w=0; w<16; w++){
        float4 h4 = *(const float4*)&h_sh[w][k4];
        acc0[w] += w00*h4.x + w01*h4.y + w02*h4.z + w03*h4.w;
        acc1[w] += w10*h4.x + w11*h4.y + w12*h4.z + w13*h4.w;
      }
    }
#pragma unroll
    for (int w=0; w<16; w++){ gsh[g0][w] = acc0[w]; gsh[g1][w] = acc1[w]; }
    __syncthreads();                                        // (G)

    float hnew[8];
#pragma unroll
    for (int u=0; u<8; u++){
      int j = ujg*8 + u;
      float gi = sigmoidf_(gsh[j][uw]);
      float gf = sigmoidf_(gsh[HC + j][uw]);
      float gg = tanhf   (gsh[2*HC + j][uw]);
      float go = sigmoidf_(gsh[3*HC + j][uw]);
      c[u] = gf*c[u] + gi*gg;
      hnew[u] = go * tanhf(c[u]);
    }
#pragma unroll
    for (int u=0; u<8; u+=4)
      *(float4*)&h_sh[uw][ujg*8 + u] = make_float4(hnew[u],hnew[u+1],hnew[u+2],hnew[u+3]);
    if (t == lw-1){
#pragma unroll
      for (int u=0; u<8; u+=4)
        *(float4*)&embeds[(size_t)(s0+uw)*384 + ujg*8 + u]
            = make_float4(hnew[u],hnew[u+1],hnew[u+2],hnew[u+3]);
    }
  }
}

// ---------------------------------------------------------------- k_gather
__global__ __launch_bounds__(256) void k_gather(
    const int* __restrict__ sentence, const float* __restrict__ word_emb,
    float* __restrict__ embeds)
{
  int blk = blockIdx.x, tid = threadIdx.x;
  int s = blk*8 + (tid >> 5);
  int lane = tid & 31;
  int idx = sentence[s];
  const float4* src = (const float4*)(word_emb + (size_t)idx*DW);
  float4* dst = (float4*)(embeds + (size_t)s*384 + 128);
  dst[lane]      = src[lane];
  dst[lane + 32] = src[lane + 32];
}

// ---------------------------------------------------------------- k_pregate
__global__ __launch_bounds__(256) void k_pregate(
    const float* __restrict__ embeds,
    const float* __restrict__ Wih_fw, const float* __restrict__ b_fw,
    const float* __restrict__ Wih_bw, const float* __restrict__ b_bw,
    float* __restrict__ pregates)
{
  int dir = blockIdx.z;
  const float* W    = dir ? Wih_bw : Wih_fw;
  const float* bias = dir ? b_bw   : b_fw;
  int t0 = blockIdx.x*64, n0 = blockIdx.y*64;
  __shared__ float a_sh[16][68];
  __shared__ float b_sh[16][68];
  int tid = threadIdx.x;
  int li = tid & 63, kq = tid >> 6;
  int ti = tid >> 4, tj = tid & 15;
  float acc[4][4];
#pragma unroll
  for (int ii=0; ii<4; ii++)
#pragma unroll
    for (int jj=0; jj<4; jj++) acc[ii][jj] = 0.0f;

  for (int k0=0; k0<384; k0+=16){
    float4 av = *(const float4*)&embeds[(size_t)(t0+li)*384 + k0 + kq*4];
    float4 bv = *(const float4*)&W     [(size_t)(n0+li)*384 + k0 + kq*4];
    __syncthreads();
    a_sh[kq*4+0][li]=av.x; a_sh[kq*4+1][li]=av.y; a_sh[kq*4+2][li]=av.z; a_sh[kq*4+3][li]=av.w;
    b_sh[kq*4+0][li]=bv.x; b_sh[kq*4+1][li]=bv.y; b_sh[kq*4+2][li]=bv.z; b_sh[kq*4+3][li]=bv.w;
    __syncthreads();
#pragma unroll
    for (int kk=0; kk<16; kk++){
      float4 a4 = *(const float4*)&a_sh[kk][ti*4];
      float4 b4 = *(const float4*)&b_sh[kk][tj*4];
      float aa[4] = {a4.x,a4.y,a4.z,a4.w};
      float bb[4] = {b4.x,b4.y,b4.z,b4.w};
#pragma unroll
      for (int ii=0; ii<4; ii++)
#pragma unroll
        for (int jj=0; jj<4; jj++) acc[ii][jj] += aa[ii]*bb[jj];
    }
  }
  float4 bias4 = *(const float4*)&bias[n0 + tj*4];
  float bb2[4] = {bias4.x,bias4.y,bias4.z,bias4.w};
#pragma unroll
  for (int ii=0; ii<4; ii++){
    float4 o = make_float4(acc[ii][0]+bb2[0], acc[ii][1]+bb2[1],
                           acc[ii][2]+bb2[2], acc[ii][3]+bb2[3]);
    *(float4*)&pregates[((size_t)dir*S_LEN + (t0+ti*4+ii))*NG + n0 + tj*4] = o;
  }
}

// ---------------------------------------------------------------- k_recurrent
// Launch 64 blocks; workers: b%8==0 -> fw slice g=b>>3 ; b%8==1 -> bw slice g=b>>3.
// Under round-robin blockIdx%8 -> XCD dispatch, each direction's 8 WGs share one XCD
// (perf heuristic only). Thread (r4=tid>>3, ke=tid&7): 4 gate rows x 32 k in VGPRs.
// h_sh padded: ph(k) = (k>>5)*36 + (k&31) -> start banks 4*ke, conflict-free b128.
__global__ __launch_bounds__(256, 1) void k_recurrent(
    const float* __restrict__ Whh_fw, const float* __restrict__ Whh_bw,
    const float* __restrict__ pregates,
    unsigned long long* hbuf,
    float* __restrict__ hout)
{
  int b = blockIdx.x;
  if ((b & 7) > 1) return;
  int dir = b & 7, g = b >> 3;
  int tid = threadIdx.x;
  const float* Whh = dir ? Whh_bw : Whh_fw;
  const float* pgb = pregates + (size_t)dir * S_LEN * NG;
  unsigned long long* hb = hbuf + (size_t)dir * 2 * H2;

  __shared__ float h_sh[8*36];
  __shared__ float gacc[128];

  int r4 = tid >> 3, ke = tid & 7;
  int q   = r4 >> 3;                 // gate block 0..3 (i,f,g,o)
  int jj4 = (4*r4) & 31;
  int row0 = q*H2 + g*32 + jj4;

  float w[4][32];
#pragma unroll
  for (int rr=0; rr<4; rr++){
    const float* wr = Whh + (size_t)(row0+rr)*H2 + ke*32;
#pragma unroll
    for (int kq=0; kq<8; kq++){
      float4 v = *(const float4*)&wr[kq*4];
      w[rr][kq*4+0]=v.x; w[rr][kq*4+1]=v.y; w[rr][kq*4+2]=v.z; w[rr][kq*4+3]=v.w;
    }
  }
  float c = 0.0f;
  h_sh[(tid>>5)*36 + (tid&31)] = 0.0f;   // h_{-1} = 0 (tid covers k=0..255)
  __syncthreads();

  // pregate prefetch pipeline
  float4 pgn = make_float4(0.f,0.f,0.f,0.f);
  {
    int t0 = dir ? (S_LEN-1) : 0;
    if (ke == 0) pgn = *(const float4*)&pgb[(size_t)t0*NG + row0];
  }

  for (int sstep=0; sstep<S_LEN; sstep++){
    float4 pg = pgn;
    if (ke == 0 && sstep+1 < S_LEN){
      int tn = dir ? (S_LEN-2-sstep) : (sstep+1);
      pgn = *(const float4*)&pgb[(size_t)tn*NG + row0];
    }

    float a0=0.f, a1=0.f, a2=0.f, a3=0.f;
    const float* hk = &h_sh[ke*36];
#pragma unroll
    for (int kq=0; kq<8; kq++){
      float4 h4 = *(const float4*)&hk[kq*4];
      a0 += w[0][kq*4+0]*h4.x + w[0][kq*4+1]*h4.y + w[0][kq*4+2]*h4.z + w[0][kq*4+3]*h4.w;
      a1 += w[1][kq*4+0]*h4.x + w[1][kq*4+1]*h4.y + w[1][kq*4+2]*h4.z + w[1][kq*4+3]*h4.w;
      a2 += w[2][kq*4+0]*h4.x + w[2][kq*4+1]*h4.y + w[2][kq*4+2]*h4.z + w[2][kq*4+3]*h4.w;
      a3 += w[3][kq*4+0]*h4.x + w[3][kq*4+1]*h4.y + w[3][kq*4+2]*h4.z + w[3][kq*4+3]*h4.w;
    }
    a0 += __shfl_xor(a0,1); a1 += __shfl_xor(a1,1); a2 += __shfl_xor(a2,1); a3 += __shfl_xor(a3,1);
    a0 += __shfl_xor(a0,2); a1 += __shfl_xor(a1,2); a2 += __shfl_xor(a2,2); a3 += __shfl_xor(a3,2);
    a0 += __shfl_xor(a0,4); a1 += __shfl_xor(a1,4); a2 += __shfl_xor(a2,4); a3 += __shfl_xor(a3,4);
    if (ke == 0)
      *(float4*)&gacc[r4*4] = make_float4(a0+pg.x, a1+pg.y, a2+pg.z, a3+pg.w);
    __syncthreads();

    if (tid < 32){
      int t = dir ? (S_LEN-1-sstep) : sstep;
      float gi = sigmoid_f(gacc[tid]);
      float gf = sigmoid_f(gacc[32+tid]);
      float gg = tanh_f  (gacc[64+tid]);
      float go = sigmoid_f(gacc[96+tid]);
      c = gf*c + gi*gg;
      float hn = go * tanh_f(c);
      unsigned long long pack =
          ((unsigned long long)__float_as_uint(hn) << 32) | (unsigned long long)(unsigned)(sstep+1);
      __hip_atomic_store(&hb[(sstep&1)*H2 + g*32 + tid], pack,
                         __ATOMIC_RELAXED, __HIP_MEMORY_SCOPE_AGENT);
      hout[(size_t)t*512 + dir*H2 + g*32 + tid] = hn;
    }
    // wave 0 polls all 256 slots (4 coalesced per lane), distributes via LDS
    if (tid < 64){
      unsigned tag = (unsigned)(sstep+1);
      unsigned long long* base = &hb[(sstep&1)*H2];
      unsigned long long v0,v1,v2,v3;
      for (;;){
        v0 = __hip_atomic_load(base+tid,     __ATOMIC_RELAXED, __HIP_MEMORY_SCOPE_AGENT);
        v1 = __hip_atomic_load(base+tid+64,  __ATOMIC_RELAXED, __HIP_MEMORY_SCOPE_AGENT);
        v2 = __hip_atomic_load(base+tid+128, __ATOMIC_RELAXED, __HIP_MEMORY_SCOPE_AGENT);
        v3 = __hip_atomic_load(base+tid+192, __ATOMIC_RELAXED, __HIP_MEMORY_SCOPE_AGENT);
        if ( ((unsigned)v0==tag) & ((unsigned)v1==tag) &
             ((unsigned)v2==tag) & ((unsigned)v3==tag) ) break;
      }
      int k0=tid, k1=tid+64, k2=tid+128, k3=tid+192;
      h_sh[(k0>>5)*36+(k0&31)] = __uint_as_float((unsigned)(v0>>32));
      h_sh[(k1>>5)*36+(k1&31)] = __uint_as_float((unsigned)(v1>>32));
      h_sh[(k2>>5)*36+(k2&31)] = __uint_as_float((unsigned)(v2>>32));
      h_sh[(k3>>5)*36+(k3&31)] = __uint_as_float((unsigned)(v3>>32));
    }
    __syncthreads();
  }
}

// ---------------------------------------------------------------- k_output
__global__ __launch_bounds__(256) void k_output(
    const float* __restrict__ hout, const float* __restrict__ outW,
    const float* __restrict__ outb, float* __restrict__ out)
{
  __shared__ float wT[128][66];
  __shared__ float hsh[32][132];
  __shared__ float lsh[32][66];
  __shared__ float msh[32][2];
  int t0 = blockIdx.x*32, tid = threadIdx.x;
  int n  = tid & 63, tg = tid >> 6;
  int sl = tid >> 3, kg = tid & 7;
  int wn = tid & 63, wk = tid >> 6;
  float acc[8];
#pragma unroll
  for (int u=0; u<8; u++) acc[u] = 0.0f;

  for (int kc=0; kc<4; kc++){
    int k0 = kc*128;
    float4 wreg[8];
#pragma unroll
    for (int e=0; e<8; e++) wreg[e] = *(const float4*)&outW[(size_t)wn*512 + k0 + wk*32 + e*4];
    float4 hreg[4];
#pragma unroll
    for (int e=0; e<4; e++) hreg[e] = *(const float4*)&hout[(size_t)(t0+sl)*512 + k0 + kg*16 + e*4];
    __syncthreads();
#pragma unroll
    for (int e=0; e<8; e++){
      int kk = wk*32 + e*4;
      wT[kk+0][wn]=wreg[e].x; wT[kk+1][wn]=wreg[e].y; wT[kk+2][wn]=wreg[e].z; wT[kk+3][wn]=wreg[e].w;
    }
#pragma unroll
    for (int e=0; e<4; e++) *(float4*)&hsh[sl][kg*16 + e*4] = hreg[e];
    __syncthreads();
#pragma unroll
    for (int kk4=0; kk4<128; kk4+=4){
      float w0 = wT[kk4+0][n], w1 = wT[kk4+1][n], w2 = wT[kk4+2][n], w3 = wT[kk4+3][n];
#pragma unroll
      for (int u=0; u<8; u++){
        float4 h4 = *(const float4*)&hsh[tg*8+u][kk4];
        acc[u] += w0*h4.x + w1*h4.y + w2*h4.z + w3*h4.w;
      }
    }
  }
  float bn = outb[n];
#pragma unroll
  for (int u=0; u<8; u++) lsh[tg*8+u][n] = acc[u] + bn;
  __syncthreads();
  if (tid < 32){
    float M = -3.4e38f;
    for (int j=0; j<NTAG; j++) M = fmaxf(M, lsh[tid][j]);
    float ssum = 0.0f;
    for (int j=0; j<NTAG; j++) ssum += expf(lsh[tid][j] - M);
    msh[tid][0] = M; msh[tid][1] = logf(ssum);
  }
  __syncthreads();
#pragma unroll
  for (int u=0; u<8; u++){
    int tt = tg*8+u;
    out[(size_t)(t0+tt)*NTAG + n] = lsh[tt][n] - msh[tt][0] - msh[tt][1];
  }
}

// ---------------------------------------------------------------- launch
extern "C" void kernel_launch(void* const* d_in, const int* in_sizes, int n_in,
                              void* d_out, int out_size, void* d_ws, size_t ws_size,
                              hipStream_t stream)
{
  (void)in_sizes; (void)n_in; (void)out_size; (void)ws_size;
  const int*   sentence = (const int*)d_in[0];
  const int*   charsets = (const int*)d_in[1];
  const int*   char_len = (const int*)d_in[2];
  const float* word_emb = (const float*)d_in[3];
  const float* char_emb = (const float*)d_in[4];
  const float* char_Wih = (const float*)d_in[5];
  const float* char_Whh = (const float*)d_in[6];
  const float* char_b   = (const float*)d_in[7];
  const float* fw_Wih   = (const float*)d_in[8];
  const float* fw_Whh   = (const float*)d_in[9];
  const float* fw_b     = (const float*)d_in[10];
  const float* bw_Wih   = (const float*)d_in[11];
  const float* bw_Whh   = (const float*)d_in[12];
  const float* bw_b     = (const float*)d_in[13];
  const float* out_W    = (const float*)d_in[14];
  const float* out_b    = (const float*)d_in[15];
  float* out = (float*)d_out;

  char* ws = (char*)d_ws;
  float* preC     = (float*)(ws);
  float* whhTc    = (float*)(ws + 262144);
  float* embeds   = (float*)(ws + 524288);
  float* pregates = (float*)(ws + 13107200);
  float* houtb    = (float*)(ws + 80216064);
  unsigned long long* hbuf = (unsigned long long*)(ws + 96993280);

  k_prep     <<<256,  512, 0, stream>>>(char_emb, char_Wih, char_Whh, char_b, preC, whhTc);
  k_char_lstm<<<512,  256, 0, stream>>>(charsets, char_len, preC, whhTc, embeds);
  k_gather   <<<1024, 256, 0, stream>>>(sentence, word_emb, embeds);
  k_pregate  <<<dim3(128,16,2), 256, 0, stream>>>(embeds, fw_Wih, fw_b, bw_Wih, bw_b, pregates);
  k_recurrent<<<64,   256, 0, stream>>>(fw_Whh, bw_Whh, pregates, hbuf, houtb);
  k_output   <<<256,  256, 0, stream>>>(houtb, out_W, out_b, out);
}